// Round 6
// baseline (1133.251 us; speedup 1.0000x reference)
//
#include <hip/hip_runtime.h>
#include <math.h>

// Problem dims
#define TB 16   // batch (tasks)
#define TT 16   // train steps
#define LL 128  // test length
#define XX 256  // x dim
#define HH 512  // hidden
#define YY 256  // y dim

#define SENTU 0xFFFFFFFFu  // -NaN bit pattern: unreachable by finite fp32 math

__device__ __forceinline__ float wred(float v) {
    v += __shfl_xor(v, 32);
    v += __shfl_xor(v, 16);
    v += __shfl_xor(v, 8);
    v += __shfl_xor(v, 4);
    v += __shfl_xor(v, 2);
    v += __shfl_xor(v, 1);
    return v;
}

// Agent-scope (through-to-MALL) store for cross-WG data.
__device__ __forceinline__ void stg(float* p, float v) {
    __hip_atomic_store(p, v, __ATOMIC_RELAXED, __HIP_MEMORY_SCOPE_AGENT);
}

// Dataflow poll: spin on the data cell itself (sc1 load, bypasses stale L2)
// until the producer's write-through lands. Returns the value.
__device__ __forceinline__ float pollf(const float* p) {
    const unsigned* u = (const unsigned*)p;
    unsigned v;
    do {
        v = __hip_atomic_load(u, __ATOMIC_RELAXED, __HIP_MEMORY_SCOPE_AGENT);
    } while (v == SENTU);
    return __uint_as_float(v);
}

// ---------------------------------------------------------------------------
// 64x64 transpose tile helper (coalesced both sides, LDS pad).
// ---------------------------------------------------------------------------
__device__ __forceinline__ void tr_tile(
    const float* __restrict__ src, float* __restrict__ dst,
    int srcW, int dstW, int ro, int co, float (*tbuf)[65], int tid)
{
    #pragma unroll
    for (int rep = 0; rep < 4; ++rep) {
        const int r = rep * 16 + (tid >> 4);
        const int c = (tid & 15) * 4;
        const float4 v = *(const float4*)&src[(long)(ro + r) * srcW + co + c];
        tbuf[r][c] = v.x; tbuf[r][c + 1] = v.y; tbuf[r][c + 2] = v.z; tbuf[r][c + 3] = v.w;
    }
    __syncthreads();
    #pragma unroll
    for (int rep = 0; rep < 4; ++rep) {
        const int c = rep * 16 + (tid >> 4);
        const int r = (tid & 15) * 4;
        float4 v;
        v.x = tbuf[r][c]; v.y = tbuf[r + 1][c]; v.z = tbuf[r + 2][c]; v.w = tbuf[r + 3][c];
        *(float4*)&dst[(long)(co + c) * dstW + ro + r] = v;
    }
}

// ---------------------------------------------------------------------------
// Fused prep kernel, 240 WGs of 256:
//  [0,64):   Z1 = tx @ W1^T + b1 (tiled GEMM) + H1[b][0] = relu
//  [64,80):  G1 gram (+1) + out[2048] = exp(loglr)
//  [80,144): WT2 = W2^T   [144,208): WT3 = W3^T   [208,240): WT4 = W4^T
// ---------------------------------------------------------------------------
__global__ __launch_bounds__(256) void k_prep(
    const float* __restrict__ W1, const float* __restrict__ b1,
    const float* __restrict__ tx,
    const float* __restrict__ W2, const float* __restrict__ W3,
    const float* __restrict__ W4, const float* __restrict__ loglr,
    float* __restrict__ Z1base, float* __restrict__ H1,
    float* __restrict__ G1, float* __restrict__ out,
    float* __restrict__ WT2, float* __restrict__ WT3, float* __restrict__ WT4)
{
    const int blk = blockIdx.x;
    const int tid = threadIdx.x;
    __shared__ float lw[64][65];
    __shared__ float lx[32][65];

    if (blk < 64) {
        const int nc = blk & 7, mc = blk >> 3;
        const int tn = tid & 31, tl = tid >> 5;
        float acc[2][4] = {};
        for (int kc = 0; kc < XX; kc += 64) {
            __syncthreads();
            #pragma unroll
            for (int rep = 0; rep < 4; ++rep) {
                const int idx4 = (rep * 256 + tid) * 4;
                const int i = idx4 >> 6, k = idx4 & 63;
                const float4 v = *(const float4*)&W1[(nc * 64 + i) * XX + kc + k];
                lw[i][k] = v.x; lw[i][k + 1] = v.y; lw[i][k + 2] = v.z; lw[i][k + 3] = v.w;
            }
            #pragma unroll
            for (int rep = 0; rep < 2; ++rep) {
                const int idx4 = (rep * 256 + tid) * 4;
                const int l = idx4 >> 6, k = idx4 & 63;
                const float4 v = *(const float4*)&tx[(mc * 32 + l) * XX + kc + k];
                lx[l][k] = v.x; lx[l][k + 1] = v.y; lx[l][k + 2] = v.z; lx[l][k + 3] = v.w;
            }
            __syncthreads();
            #pragma unroll 4
            for (int k = 0; k < 64; ++k) {
                const float w0 = lw[tn][k], w1 = lw[tn + 32][k];
                const float x0 = lx[tl][k],      x1 = lx[tl + 8][k];
                const float x2 = lx[tl + 16][k], x3 = lx[tl + 24][k];
                acc[0][0] += w0 * x0; acc[0][1] += w0 * x1;
                acc[0][2] += w0 * x2; acc[0][3] += w0 * x3;
                acc[1][0] += w1 * x0; acc[1][1] += w1 * x1;
                acc[1][2] += w1 * x2; acc[1][3] += w1 * x3;
            }
        }
        #pragma unroll
        for (int i = 0; i < 2; ++i) {
            const int n = nc * 64 + tn + i * 32;
            const float bv = b1[n];
            #pragma unroll
            for (int j = 0; j < 4; ++j) {
                const int m = mc * 32 + tl + j * 8;
                const float v = acc[i][j] + bv;
                Z1base[m * HH + n] = v;
                if ((m & 15) == 0) H1[m * HH + n] = fmaxf(v, 0.0f);  // t==0
            }
        }
    } else if (blk < 80) {
        const int b = blk - 64;
        float (*sx)[XX + 1] = (float (*)[XX + 1])&lw[0][0];  // 16x257 fits in lw
        #pragma unroll
        for (int rep = 0; rep < 16; ++rep) {
            const int flat = rep * 256 + tid;
            const int s = flat >> 8, k = flat & 255;
            sx[s][k] = tx[(b * TT + s) * XX + k];
        }
        __syncthreads();
        if (b == 0 && tid == 0) out[2048] = expf(loglr[0]);
        const int s = tid >> 4, t = tid & 15;
        float a = 0.0f;
        #pragma unroll 8
        for (int k = 0; k < XX; ++k) a += sx[s][k] * sx[t][k];
        G1[(b * TT + s) * TT + t] = a + 1.0f;
    } else if (blk < 144) {
        const int id = blk - 80;
        tr_tile(W2, WT2, HH, HH, (id & 7) * 64, (id >> 3) * 64,
                (float (*)[65])&lw[0][0], tid);
    } else if (blk < 208) {
        const int id = blk - 144;
        tr_tile(W3, WT3, HH, HH, (id & 7) * 64, (id >> 3) * 64,
                (float (*)[65])&lw[0][0], tid);
    } else {
        const int id = blk - 208;  // W4 [256][512] -> WT4 [512][256]
        tr_tile(W4, WT4, HH, YY, (id & 3) * 64, (id >> 2) * 64,
                (float (*)[65])&lw[0][0], tid);
    }
}

// ---------------------------------------------------------------------------
// Inner-loop stages. WG = (b, hc). All per-example bases pre-folded.
// Fresh inputs arrive via sentinel-poll; history via plain (validated) loads.
// ---------------------------------------------------------------------------
template <int OUT, bool RELU, bool GATE, bool PLUSONE, bool BIAS>
__device__ __forceinline__ void fwd_stage(
    const float* __restrict__ WT,     // [HH][OUT] transposed weights
    const float* __restrict__ bias,
    const float* __restrict__ hist,   // [TT][HH] per-b; fresh = [t]
    const float* __restrict__ Darr,   // [TT][OUT] per-b
    const float* __restrict__ tgt,    // gate row (b,t) when GATE
    float* __restrict__ outv,
    int hc, int t, float lr,
    float* s_in, float* s_c, float (*s_cp)[17], float* s_red, float* lwT,
    int tid)
{
    constexpr int RPW  = OUT / 8;     // rows per WG: 64 or 32
    constexpr int KQ   = 256 / RPW;   // k-split
    constexpr int KL   = 128 / KQ;    // per-thread k per 128-tile
    constexpr int STR  = RPW + 1;
    constexpr int RPW4 = RPW / 4;

    const float* fresh = &hist[t * HH];
    s_in[tid]       = pollf(&fresh[tid]);
    s_in[tid + 256] = pollf(&fresh[tid + 256]);
    __atomic_signal_fence(__ATOMIC_ACQUIRE);
    __syncthreads();

    {   // coefficient partials: c[s] = hist_s . x_t (+1)
        const int s = tid >> 4, ch = tid & 15;
        if (s < t) {
            const float* hp = &hist[s * HH + ch * 32];
            const float* xp = &s_in[ch * 32];
            float p = 0.f;
            #pragma unroll
            for (int j = 0; j < 32; j += 4) {
                const float4 h4 = *(const float4*)&hp[j];
                p += h4.x * xp[j] + h4.y * xp[j + 1] + h4.z * xp[j + 2] + h4.w * xp[j + 3];
            }
            s_cp[s][ch] = p;
        }
    }
    __syncthreads();
    if (tid < 16 && tid < t) {
        float c = 0.f;
        #pragma unroll
        for (int ch = 0; ch < 16; ++ch) c += s_cp[tid][ch];
        s_c[tid] = c + (PLUSONE ? 1.0f : 0.0f);
    }

    // matvec: conflict-free LDS staging from transposed W, thread-per-row
    const int rloc = tid % RPW, kq = tid / RPW;
    float acc = 0.f;
    for (int kc = 0; kc < HH; kc += 128) {
        __syncthreads();
        constexpr int REPS = (128 * RPW4) / 256;
        #pragma unroll
        for (int rep = 0; rep < REPS; ++rep) {
            const int flat = rep * 256 + tid;
            const int k = flat / RPW4, i4 = (flat % RPW4) * 4;
            const float4 wv = *(const float4*)&WT[(long)(kc + k) * OUT + hc * RPW + i4];
            *(float4*)&lwT[k * STR + i4] = wv;
        }
        __syncthreads();
        const float* xp = &s_in[kc + kq * KL];
        const float* wp = &lwT[(kq * KL) * STR + rloc];
        #pragma unroll
        for (int k = 0; k < KL; ++k) acc += wp[k * STR] * xp[k];
    }
    s_red[tid] = acc;
    __syncthreads();

    if (tid < RPW) {
        const int row = hc * RPW + tid;
        float z = 0.f;
        #pragma unroll
        for (int q = 0; q < KQ; ++q) z += s_red[q * RPW + tid];
        if (t > 0) {
            float cr = 0.f;
            #pragma unroll
            for (int s = 0; s < TT; ++s) {     // clamp-unrolled: parallel loads,
                const int ss = (s < t) ? s : 0; // never touches unwritten cells
                const float d  = Darr[ss * OUT + row];
                const float cc = (s < t) ? s_c[s] : 0.f;
                cr += d * cc;
            }
            z -= lr * cr;
        }
        if constexpr (BIAS) z += bias[row];
        if constexpr (RELU) z = fmaxf(z, 0.0f);
        if constexpr (GATE) z *= tgt[row];
        stg(&outv[row], z);
    }
}

__device__ __forceinline__ void bwd4_stage(
    const float* __restrict__ W4, const float* __restrict__ tyb,
    const float* __restrict__ tgb, const float* __restrict__ LOGb,
    const float* __restrict__ HGb, float* __restrict__ D4b,
    float* __restrict__ D3b,
    int hc, int t, float lr,
    float* s_dlg, float* s_c, float (*s_cp)[17], float* s_red,
    int tid, int lane, int w)
{
    const float lg = pollf(&LOGb[t * YY + tid]);
    __atomic_signal_fence(__ATOMIC_ACQUIRE);
    s_dlg[tid] = (lg - tyb[t * YY + tid]) * (2.0f / YY);
    __syncthreads();
    if (hc == 0) stg(&D4b[t * YY + tid], s_dlg[tid]);

    {   // bc[s] = lr * (D4_s . dlg)
        const int s = tid >> 4, ch = tid & 15;
        if (s < t) {
            const float* dp = &D4b[s * YY + ch * 16];
            const float* xp = &s_dlg[ch * 16];
            float p = 0.f;
            #pragma unroll
            for (int j = 0; j < 16; j += 4) {
                const float4 d4 = *(const float4*)&dp[j];
                p += d4.x * xp[j] + d4.y * xp[j + 1] + d4.z * xp[j + 2] + d4.w * xp[j + 3];
            }
            s_cp[s][ch] = p;
        }
    }
    __syncthreads();
    if (tid < 16 && tid < t) {
        float c = 0.f;
        #pragma unroll
        for (int ch = 0; ch < 16; ++ch) c += s_cp[tid][ch];
        s_c[tid] = lr * c;
    }

    const int h = hc * 64 + lane;
    float acc = 0.f;
    for (int y = w * 64; y < w * 64 + 64; ++y) acc += W4[(long)y * HH + h] * s_dlg[y];
    s_red[w * 64 + lane] = acc;
    __syncthreads();

    if (tid < 64) {
        const int hh = hc * 64 + tid;
        float sum = s_red[tid] + s_red[64 + tid] + s_red[128 + tid] + s_red[192 + tid];
        if (t > 0) {
            #pragma unroll
            for (int s = 0; s < TT; ++s) {
                const int ss = (s < t) ? s : 0;
                const float hv = HGb[ss * HH + hh];
                const float cc = (s < t) ? s_c[s] : 0.f;
                sum -= hv * cc;
            }
        }
        const float g = tgb[t * HH + hh];
        const float m = (HGb[t * HH + hh] > 0.0f) ? 1.0f : 0.0f;
        stg(&D3b[t * HH + hh], sum * g * m);
    }
}

template <bool EPI>
__device__ __forceinline__ void bwd_stage(
    const float* __restrict__ W,     // original row-major (columns read)
    const float* __restrict__ Din,   // [TT][HH] per-b; fresh = [t]
    const float* __restrict__ hist,  // [TT][HH] per-b (mask + history)
    float* __restrict__ Dout,
    const float* __restrict__ Z1b, const float* __restrict__ G1b,
    float* __restrict__ H1b,
    int hc, int t, float lr,
    float* s_v, float* s_c, float (*s_cp)[17], float* s_red, float* s_g,
    int tid, int lane, int w)
{
    const float* fresh = &Din[t * HH];
    s_v[tid]       = pollf(&fresh[tid]);
    s_v[tid + 256] = pollf(&fresh[tid + 256]);
    __atomic_signal_fence(__ATOMIC_ACQUIRE);
    if (EPI && tid < TT)
        s_g[tid] = G1b[tid * TT + ((t + 1 < TT) ? (t + 1) : 0)];
    __syncthreads();

    {   // bc[s] = lr * (Din_s . dz_t)
        const int s = tid >> 4, ch = tid & 15;
        if (s < t) {
            const float* dp = &Din[s * HH + ch * 32];
            const float* xp = &s_v[ch * 32];
            float p = 0.f;
            #pragma unroll
            for (int j = 0; j < 32; j += 4) {
                const float4 d4 = *(const float4*)&dp[j];
                p += d4.x * xp[j] + d4.y * xp[j + 1] + d4.z * xp[j + 2] + d4.w * xp[j + 3];
            }
            s_cp[s][ch] = p;
        }
    }
    __syncthreads();
    if (tid < 16 && tid < t) {
        float c = 0.f;
        #pragma unroll
        for (int ch = 0; ch < 16; ++ch) c += s_cp[tid][ch];
        s_c[tid] = lr * c;
    }

    const int h = hc * 64 + lane;
    float acc = 0.f;
    for (int i = w * 128; i < w * 128 + 128; ++i) acc += W[(long)i * HH + h] * s_v[i];
    s_red[w * 64 + lane] = acc;
    __syncthreads();

    if (tid < 64) {
        const int hh = hc * 64 + tid;
        float sum = s_red[tid] + s_red[64 + tid] + s_red[128 + tid] + s_red[192 + tid];
        if (t > 0) {
            #pragma unroll
            for (int s = 0; s < TT; ++s) {
                const int ss = (s < t) ? s : 0;
                const float hv = hist[ss * HH + hh];
                const float cc = (s < t) ? s_c[s] : 0.f;
                sum -= hv * cc;
            }
        }
        const float m = (hist[t * HH + hh] > 0.0f) ? 1.0f : 0.0f;
        const float dz = sum * m;
        stg(&Dout[t * HH + hh], dz);
        if (EPI && (t + 1 < TT)) {
            float cr = dz * s_g[t];
            if (t > 0) {
                #pragma unroll
                for (int s = 0; s < TT; ++s) {
                    const int ss = (s < t) ? s : 0;
                    const float dv = Dout[ss * HH + hh];   // own prior writes
                    const float gg = (s < t) ? s_g[s] : 0.f;
                    cr += dv * gg;
                }
            }
            const float z = Z1b[(t + 1) * HH + hh];
            stg(&H1b[(t + 1) * HH + hh], fmaxf(z - lr * cr, 0.0f));
        }
    }
}

// ---------------------------------------------------------------------------
// Persistent inner loop: 16 steps x 6 stages, ZERO barriers — pure dataflow.
// grid: 128 WGs of 256. wid = hc*16 + b (example's 8 WGs share an XCD).
// ---------------------------------------------------------------------------
__global__ __launch_bounds__(256) void k_inner(
    const float* __restrict__ W2, const float* __restrict__ b2,
    const float* __restrict__ W3, const float* __restrict__ b3,
    const float* __restrict__ W4,
    const float* __restrict__ WT2, const float* __restrict__ WT3,
    const float* __restrict__ WT4,
    const float* __restrict__ ty, const float* __restrict__ tg,
    const float* __restrict__ Z1base, const float* __restrict__ G1,
    float* __restrict__ H1, float* __restrict__ H2, float* __restrict__ HG,
    float* __restrict__ D1, float* __restrict__ D2, float* __restrict__ D3,
    float* __restrict__ D4, float* __restrict__ LOG,
    const float* __restrict__ loglr)
{
    const int wid = blockIdx.x;
    const int b = wid & 15, hc = wid >> 4;
    const int tid = threadIdx.x, lane = tid & 63, w = tid >> 6;
    const float lr = expf(loglr[0]);

    const float* tyb = ty + b * TT * YY;
    const float* tgb = tg + b * TT * HH;
    const float* Z1b = Z1base + b * TT * HH;
    const float* G1b = G1 + b * TT * TT;
    float* H1b = H1 + b * TT * HH;
    float* H2b = H2 + b * TT * HH;
    float* HGb = HG + b * TT * HH;
    float* D1b = D1 + b * TT * HH;
    float* D2b = D2 + b * TT * HH;
    float* D3b = D3 + b * TT * HH;
    float* D4b = D4 + b * TT * YY;
    float* LOGb = LOG + b * TT * YY;

    __shared__ float s_in[HH];
    __shared__ float s_c[TT];
    __shared__ float s_cp[TT][17];
    __shared__ float s_red[256];
    __shared__ float s_g[TT];
    __shared__ float lwT[128 * 65];

    for (int t = 0; t < TT; ++t) {
        // F2: h2 = relu(W2@h1 + b2 - lr*sum D2[s]*(h1_s.h1_t+1))
        fwd_stage<HH, true, false, true, true>(
            WT2, b2, H1b, D2b, nullptr, H2b + t * HH,
            hc, t, lr, s_in, s_c, s_cp, s_red, lwT, tid);
        // F3: hg = relu(z3) * gate_t
        fwd_stage<HH, true, true, true, true>(
            WT3, b3, H2b, D3b, tgb + t * HH, HGb + t * HH,
            hc, t, lr, s_in, s_c, s_cp, s_red, lwT, tid);
        // F4: logit
        fwd_stage<YY, false, false, false, false>(
            WT4, nullptr, HGb, D4b, nullptr, LOGb + t * YY,
            hc, t, lr, s_in, s_c, s_cp, s_red, lwT, tid);
        // B4 -> D4[t], D3[t]
        bwd4_stage(W4, tyb, tgb, LOGb, HGb, D4b, D3b,
                   hc, t, lr, s_in, s_c, s_cp, s_red, tid, lane, w);
        // B3 -> D2[t]
        bwd_stage<false>(W3, D3b, H2b, D2b, nullptr, nullptr, nullptr,
                         hc, t, lr, s_in, s_c, s_cp, s_red, s_g, tid, lane, w);
        // B2 -> D1[t] + h1[t+1]
        bwd_stage<true>(W2, D2b, H1b, D1b, Z1b, G1b, H1b,
                        hc, t, lr, s_in, s_c, s_cp, s_red, s_g, tid, lane, w);
    }
}

// ---------------------------------------------------------------------------
// Phase-2 ip (GEMM-style): ip[b][s][l] = A[b][s].(act[b][l]*?tg) (+1)
// ---------------------------------------------------------------------------
template <int K, bool PLUSONE, bool GATE>
__global__ __launch_bounds__(256) void k_ip(
    const float* __restrict__ A, const float* __restrict__ act,
    const float* __restrict__ tg, float* __restrict__ ip)
{
    const int b = blockIdx.x >> 3, lc = blockIdx.x & 7;
    const int tid = threadIdx.x;
    const int s = tid >> 4, j = tid & 15;
    __shared__ float sA[TT][68];
    __shared__ float sX[TT][68];
    float acc = 0.f;
    for (int kc = 0; kc < K; kc += 64) {
        __syncthreads();
        {
            const int idx4 = tid * 4;
            const int r = idx4 >> 6, k = idx4 & 63;
            const float4 va = *(const float4*)&A[((long)b * TT + r) * K + kc + k];
            sA[r][k] = va.x; sA[r][k + 1] = va.y; sA[r][k + 2] = va.z; sA[r][k + 3] = va.w;
            float4 vx = *(const float4*)&act[((long)b * LL + lc * 16 + r) * K + kc + k];
            if constexpr (GATE) {
                const float4 g = *(const float4*)&tg[((long)b * LL + lc * 16 + r) * K + kc + k];
                vx.x *= g.x; vx.y *= g.y; vx.z *= g.z; vx.w *= g.w;
            }
            sX[r][k] = vx.x; sX[r][k + 1] = vx.y; sX[r][k + 2] = vx.z; sX[r][k + 3] = vx.w;
        }
        __syncthreads();
        #pragma unroll 8
        for (int k = 0; k < 64; ++k) acc += sA[s][k] * sX[j][k];
    }
    ip[((long)b * TT + s) * LL + lc * 16 + j] = acc + (PLUSONE ? 1.0f : 0.0f);
}

// ---------------------------------------------------------------------------
// Phase-2 layer: out[b][l][n] = post( W@actg + bias - lr*sum_s D[s][n]*ip[s][l] )
// ---------------------------------------------------------------------------
template <int K, int OUT, bool RELU, bool BIAS, bool GATEIN>
__global__ __launch_bounds__(256) void k_layer(
    const float* __restrict__ W, const float* __restrict__ bias,
    const float* __restrict__ act, const float* __restrict__ tg,
    const float* __restrict__ IPa, const float* __restrict__ Dl,
    float* __restrict__ outp, const float* __restrict__ loglr)
{
    constexpr int NC = OUT / 64;
    const int blk = blockIdx.x;
    const int b = blk / (NC * 4);
    const int rem = blk % (NC * 4);
    const int nc = rem / 4, lc = rem % 4;
    const int base_n = nc * 64, base_l = lc * 32;
    const int tid = threadIdx.x;
    const int tn = tid & 31, tl = tid >> 5;
    const float lr = expf(loglr[0]);

    __shared__ float lw[64][65];
    __shared__ float lx[32][65];
    __shared__ float sD[TT][64];
    __shared__ float sip[TT][33];

    #pragma unroll
    for (int rep = 0; rep < 4; ++rep) {
        const int flat = rep * 256 + tid;
        const int s = flat >> 6, n = flat & 63;
        sD[s][n] = Dl[(b * TT + s) * OUT + base_n + n];
    }
    #pragma unroll
    for (int rep = 0; rep < 2; ++rep) {
        const int flat = rep * 256 + tid;
        const int s = flat >> 5, l = flat & 31;
        sip[s][l] = IPa[((long)b * TT + s) * LL + base_l + l];
    }

    float acc[2][4] = {};
    for (int kc = 0; kc < K; kc += 64) {
        __syncthreads();
        #pragma unroll
        for (int rep = 0; rep < 4; ++rep) {
            const int idx4 = (rep * 256 + tid) * 4;
            const int i = idx4 >> 6, k = idx4 & 63;
            const float4 v = *(const float4*)&W[(long)(base_n + i) * K + kc + k];
            lw[i][k] = v.x; lw[i][k + 1] = v.y; lw[i][k + 2] = v.z; lw[i][k + 3] = v.w;
        }
        #pragma unroll
        for (int rep = 0; rep < 2; ++rep) {
            const int idx4 = (rep * 256 + tid) * 4;
            const int l = idx4 >> 6, k = idx4 & 63;
            float4 v = *(const float4*)&act[((long)b * LL + base_l + l) * K + kc + k];
            if constexpr (GATEIN) {
                const float4 g = *(const float4*)&tg[((long)b * LL + base_l + l) * K + kc + k];
                v.x *= g.x; v.y *= g.y; v.z *= g.z; v.w *= g.w;
            }
            lx[l][k] = v.x; lx[l][k + 1] = v.y; lx[l][k + 2] = v.z; lx[l][k + 3] = v.w;
        }
        __syncthreads();
        #pragma unroll 4
        for (int k = 0; k < 64; ++k) {
            const float w0 = lw[tn][k], w1 = lw[tn + 32][k];
            const float x0 = lx[tl][k],      x1 = lx[tl + 8][k];
            const float x2 = lx[tl + 16][k], x3 = lx[tl + 24][k];
            acc[0][0] += w0 * x0; acc[0][1] += w0 * x1;
            acc[0][2] += w0 * x2; acc[0][3] += w0 * x3;
            acc[1][0] += w1 * x0; acc[1][1] += w1 * x1;
            acc[1][2] += w1 * x2; acc[1][3] += w1 * x3;
        }
    }

    #pragma unroll
    for (int i = 0; i < 2; ++i) {
        const int n = base_n + tn + i * 32;
        const float bv = BIAS ? bias[n] : 0.0f;
        #pragma unroll
        for (int j = 0; j < 4; ++j) {
            const int l = base_l + tl + j * 8;
            float corr = 0.0f;
            #pragma unroll
            for (int s = 0; s < TT; ++s)
                corr += sD[s][tn + i * 32] * sip[s][tl + j * 8];
            float v = acc[i][j] + bv - lr * corr;
            if constexpr (RELU) v = fmaxf(v, 0.0f);
            outp[((long)b * LL + l) * OUT + n] = v;
        }
    }
}

// ---------------------------------------------------------------------------
__global__ __launch_bounds__(64) void k_loss(
    const float* __restrict__ logit, const float* __restrict__ tey,
    float* __restrict__ loss, float* __restrict__ evalo)
{
    const int idx = blockIdx.x;
    const int lane = threadIdx.x;
    float a = 0.0f;
    #pragma unroll
    for (int j = 0; j < 4; ++j) {
        const float d = logit[(long)idx * YY + lane * 4 + j] -
                        tey[(long)idx * YY + lane * 4 + j];
        a += d * d;
    }
    a = wred(a);
    if (lane == 0) {
        const float v = a * (1.0f / YY);
        loss[idx] = v;
        evalo[idx] = v;
    }
}

// ---------------------------------------------------------------------------
extern "C" void kernel_launch(void* const* d_in, const int* in_sizes, int n_in,
                              void* d_out, int out_size, void* d_ws, size_t ws_size,
                              hipStream_t stream)
{
    const float* tx    = (const float*)d_in[0];
    const float* ty    = (const float*)d_in[1];
    const float* tex   = (const float*)d_in[2];
    const float* tey   = (const float*)d_in[3];
    const float* tg    = (const float*)d_in[4];
    const float* teg   = (const float*)d_in[5];
    const float* W1    = (const float*)d_in[6];
    const float* b1    = (const float*)d_in[7];
    const float* W2    = (const float*)d_in[8];
    const float* b2    = (const float*)d_in[9];
    const float* W3    = (const float*)d_in[10];
    const float* b3    = (const float*)d_in[11];
    const float* W4    = (const float*)d_in[12];
    const float* loglr = (const float*)d_in[13];

    float* out = (float*)d_out;
    float* ws  = (float*)d_ws;

    // workspace layout (floats)
    float* Z1base = ws;                      // 131072
    float* G1     = ws + 131072;             // 4096
    float* SENT   = ws + 135168;             // sentinel block start
    float* H1     = SENT;                    // 131072
    float* H2     = H1 + 131072;             // 131072
    float* HG     = H2 + 131072;             // 131072
    float* D2     = HG + 131072;             // 131072
    float* D3     = D2 + 131072;             // 131072
    float* LOG    = D3 + 131072;             // 65536  (end of sentinel block)
    float* D1     = LOG + 65536;             // 131072
    float* D4     = D1 + 131072;             // 65536
    float* IP     = D4 + 65536;              // 32768
    float* WT2    = IP + 32768;              // 262144
    float* WT3    = WT2 + 262144;            // 262144
    float* WT4    = WT3 + 262144;            // 131072
    float* ActA   = WT4 + 131072;            // 1048576
    float* ActB   = ActA + 1048576;          // 1048576

    // Sentinel-fill the polled arrays (H1,H2,HG,D2,D3,LOG = 720896 floats).
    hipMemsetAsync(SENT, 0xFF, 720896 * sizeof(float), stream);

    k_prep<<<240, 256, 0, stream>>>(W1, b1, tx, W2, W3, W4, loglr,
                                    Z1base, H1, G1, out, WT2, WT3, WT4);

    k_inner<<<128, 256, 0, stream>>>(W2, b2, W3, b3, W4, WT2, WT3, WT4,
                                     ty, tg, Z1base, G1, H1, H2, HG,
                                     D1, D2, D3, D4, LOG, loglr);

    // ---- Phase 2: test-set forward with final (rank-16-corrected) weights ----
    k_ip<XX, true, false><<<TB * 8, 256, 0, stream>>>(tx, tex, nullptr, IP);
    k_layer<XX, HH, true, true, false><<<TB * 8 * 4, 256, 0, stream>>>(
        W1, b1, tex, nullptr, IP, D1, ActA, loglr);

    k_ip<HH, true, false><<<TB * 8, 256, 0, stream>>>(H1, ActA, nullptr, IP);
    k_layer<HH, HH, true, true, false><<<TB * 8 * 4, 256, 0, stream>>>(
        W2, b2, ActA, nullptr, IP, D2, ActB, loglr);

    k_ip<HH, true, false><<<TB * 8, 256, 0, stream>>>(H2, ActB, nullptr, IP);
    k_layer<HH, HH, true, true, false><<<TB * 8 * 4, 256, 0, stream>>>(
        W3, b3, ActB, nullptr, IP, D3, ActA, loglr);

    k_ip<HH, false, true><<<TB * 8, 256, 0, stream>>>(HG, ActA, teg, IP);
    k_layer<HH, YY, false, false, true><<<TB * 4 * 4, 256, 0, stream>>>(
        W4, nullptr, ActA, teg, IP, D4, out + 4097, loglr);

    k_loss<<<TB * LL, 64, 0, stream>>>(out + 4097, tey, out, out + 2049);
}